// Round 12
// baseline (26.255 us; speedup 1.0000x reference)
//
#include <hip/hip_runtime.h>

namespace {

constexpr int kS = 7;
constexpr int kC = 20;
constexpr int kN = 8;
constexpr int kBS = 16384;
constexpr int kCells = kBS * kS * kS;   // 802816 = 3136 * 256
constexpr int kTile = 256;              // cells per block (= block size)
constexpr int kBlocks = kCells / kTile; // 3136
constexpr int kF = 30;                  // floats per cell (120 B)
constexpr float kLambdaCoord = 5.0f;
constexpr float kLambdaNoobj = 0.5f;
constexpr float kEps = 1e-6f;

typedef const __attribute__((address_space(1))) unsigned int gu32;
typedef __attribute__((address_space(3))) unsigned int lu32;

__global__ __launch_bounds__(256) void yolo_loss_kernel(
    const float* __restrict__ outputs,   // [BS,7,7,30]
    const float* __restrict__ gt_boxes,  // [BS,8,4]
    const int* __restrict__ gt_labels,   // [BS,8]
    float* __restrict__ partials) {      // [kBlocks]
  __shared__ float lds[kTile * kF];      // 30 KB transpose buffer
  __shared__ float ws[4];

  const int tid = threadIdx.x;
  const int lane = tid & 63;
  const int w = tid >> 6;                // wave id, uniform per wave

  // ---- WAVE-PRIVATE async DMA stage: wave w stages its own 64 cells
  //      (7680 B) as 7 full 1 KB global_load_lds + 1 half (lanes 0-31).
  //      No __syncthreads: each lane later reads only its own wave's slice.
  {
    const char* srcb = reinterpret_cast<const char*>(outputs) +
                       ((size_t)blockIdx.x * kTile + (size_t)w * 64) * 120;
    char* dstb = reinterpret_cast<char*>(lds) + w * 7680;
#pragma unroll
    for (int k = 0; k < 7; ++k) {
      __builtin_amdgcn_global_load_lds((gu32*)(srcb + k * 1024 + lane * 16),
                                       (lu32*)(dstb + k * 1024 + lane * 16),
                                       16, 0, 0);
    }
    if (lane < 32) {
      __builtin_amdgcn_global_load_lds((gu32*)(srcb + 7168 + lane * 16),
                                       (lu32*)(dstb + 7168 + lane * 16),
                                       16, 0, 0);
    }
  }

  // ---- gt loads issue now; latency overlaps the DMA ----
  const int c = blockIdx.x * kTile + tid;
  const int bs = c / (kS * kS);
  float g[kN][4];
  const float4* gb4 =
      reinterpret_cast<const float4*>(gt_boxes + (size_t)bs * kN * 4);
#pragma unroll
  for (int n = 0; n < kN; ++n) {
    float4 v = gb4[n];
    g[n][0] = v.x; g[n][1] = v.y; g[n][2] = v.z; g[n][3] = v.w;
  }
  const int4* lb4 = reinterpret_cast<const int4*>(gt_labels + (size_t)bs * kN);
  const int4 lab0 = lb4[0];
  const int4 lab1 = lb4[1];

  // ---- precompute gt corners/areas once (overlaps DMA flight) ----
  float gx1[kN], gx2[kN], gy1[kN], gy2[kN], ga[kN];
#pragma unroll
  for (int n = 0; n < kN; ++n) {
    gx1[n] = g[n][0] - g[n][2] * 0.5f;
    gx2[n] = g[n][0] + g[n][2] * 0.5f;
    gy1[n] = g[n][1] - g[n][3] * 0.5f;
    gy2[n] = g[n][1] + g[n][3] * 0.5f;
    ga[n]  = g[n][2] * g[n][3];
  }

  // ---- wave-local drain of the DMA (also covers gt loads) ----
  asm volatile("s_waitcnt vmcnt(0)" ::: "memory");

  // per-thread cell in LDS; word-stride 30 across lanes -> 2-way bank
  // aliasing only (free on CDNA4). 8B-aligned -> float2 (ds_read_b64).
  const float* x = lds + tid * kF;
  const float2* x2 = reinterpret_cast<const float2*>(x);

  // ---- box part: 5 x ds_read_b64 -> registers ----
  const float2 v0 = x2[0], v1 = x2[1], v2 = x2[2], v3 = x2[3], v4 = x2[4];
  // b0: x=v0.x y=v0.y w=v1.x h=v1.y conf=v2.x
  // b1: x=v2.y y=v3.x w=v3.y h=v4.x conf=v4.y

  const float p0x1 = v0.x - v1.x * 0.5f, p0x2 = v0.x + v1.x * 0.5f;
  const float p0y1 = v0.y - v1.y * 0.5f, p0y2 = v0.y + v1.y * 0.5f;
  const float pa0 = v1.x * v1.y;
  const float p1x1 = v2.y - v3.y * 0.5f, p1x2 = v2.y + v3.y * 0.5f;
  const float p1y1 = v3.x - v4.x * 0.5f, p1y2 = v3.x + v4.x * 0.5f;
  const float pa1 = v3.y * v4.x;

  // ---- fused IOU + argmax scan in FRACTION form: iou=a/b compared via
  //      cross-multiplication (all denominators > 0). One rcp at the end
  //      instead of 16. First-max-wins strict > matches jnp.argmax. ----
  float bn = 0.0f, bd = 1.0f;   // running best (num, den)
  bool bb = false;              // best_b at the running argmax position
#pragma unroll
  for (int n = 0; n < kN; ++n) {
    const float iw0 = fmaxf(fminf(p0x2, gx2[n]) - fmaxf(p0x1, gx1[n]), 0.0f);
    const float ih0 = fmaxf(fminf(p0y2, gy2[n]) - fmaxf(p0y1, gy1[n]), 0.0f);
    const float i0n = iw0 * ih0;
    const float i0d = pa0 + ga[n] - i0n + kEps;
    const float iw1 = fmaxf(fminf(p1x2, gx2[n]) - fmaxf(p1x1, gx1[n]), 0.0f);
    const float ih1 = fmaxf(fminf(p1y2, gy2[n]) - fmaxf(p1y1, gy1[n]), 0.0f);
    const float i1n = iw1 * ih1;
    const float i1d = pa1 + ga[n] - i1n + kEps;

    const bool c01 = (i1n * i0d) > (i0n * i1d);   // i1 > i0 strictly
    const float mn = c01 ? i1n : i0n;
    const float md = c01 ? i1d : i0d;
    if (n == 0) {
      bn = mn; bd = md; bb = c01;
    } else {
      const bool cb = (mn * bd) > (bn * md);      // m > best strictly
      bn = cb ? mn : bn;
      bd = cb ? md : bd;
      bb = cb ? c01 : bb;
    }
  }
  const float best_iou = bn * __builtin_amdgcn_rcpf(bd);
  const bool has_obj = bn > 0.0f;   // == (best_iou > 0)

  // ---- selections (reference quirk: best_b indexes gt_boxes' N axis) ----
  const float gsx = bb ? g[1][0] : g[0][0];
  const float gsy = bb ? g[1][1] : g[0][1];
  const float gsw = bb ? g[1][2] : g[0][2];
  const float gsh = bb ? g[1][3] : g[0][3];
  const float psx = bb ? v2.y : v0.x;
  const float psy = bb ? v3.x : v0.y;
  const float psw = bb ? v3.y : v1.x;
  const float psh = bb ? v4.x : v1.y;
  const float psc = bb ? v4.y : v2.x;

  // ---- localization + confidence (sqrt AFTER select: 2 sqrts not 4) ----
  const float dx = psx - gsx;
  const float dy = psy - gsy;
  const float dw = __builtin_amdgcn_sqrtf(psw) - __builtin_amdgcn_sqrtf(gsw);
  const float dh = __builtin_amdgcn_sqrtf(psh) - __builtin_amdgcn_sqrtf(gsh);
  const float loc = kLambdaCoord * (dx * dx + dy * dy + dw * dw + dh * dh);
  const float conf_obj = (psc - best_iou) * (psc - best_iou);

  // ---- log-sum-exp over 20 classes via 10 float2 reads (inputs in [0,1):
  //      no max pass); 4 accumulators shorten the dependence chain ----
  float seA = 0.0f, seB = 0.0f, seC = 0.0f, seD = 0.0f;
#pragma unroll
  for (int j = 0; j < 10; ++j) {
    const float2 cv = x2[5 + j];
    if (j & 1) {
      seC += __expf(cv.x);
      seD += __expf(cv.y);
    } else {
      seA += __expf(cv.x);
      seB += __expf(cv.y);
    }
  }
  const float lse = __logf((seA + seB) + (seC + seD));

  // ---- CE over the 8 labels (dynamic LDS gather) ----
  float s8 = 0.0f;
  s8 += x[10 + lab0.x] + x[10 + lab0.y] + x[10 + lab0.z] + x[10 + lab0.w];
  s8 += x[10 + lab1.x] + x[10 + lab1.y] + x[10 + lab1.z] + x[10 + lab1.w];
  const float ce = lse - 0.125f * s8;   // == -(s8 - 8*lse)/8

  // ---- noobj (conf values already in registers) ----
  const float noobj = kLambdaNoobj * (v2.x * v2.x + v4.y * v4.y);

  float val = has_obj ? (loc + conf_obj + ce) : noobj;

  // ---- block reduction: wave64 shuffle, then LDS across the 4 waves ----
#pragma unroll
  for (int off = 32; off > 0; off >>= 1) val += __shfl_down(val, off, 64);
  if (lane == 0) ws[w] = val;
  __syncthreads();
  if (tid == 0) {
    partials[blockIdx.x] = ws[0] + ws[1] + ws[2] + ws[3];  // NO atomic
  }
}

__global__ __launch_bounds__(256) void reduce_kernel(
    const float* __restrict__ partials, float* __restrict__ out) {
  // 3136 floats = 784 float4; 256 threads -> 4 rounds
  const float4* p4 = reinterpret_cast<const float4*>(partials);
  float s = 0.0f;
  for (int i = threadIdx.x; i < kBlocks / 4; i += 256) {
    const float4 v = p4[i];
    s += (v.x + v.y) + (v.z + v.w);
  }
#pragma unroll
  for (int off = 32; off > 0; off >>= 1) s += __shfl_down(s, off, 64);
  __shared__ float ws[4];
  const int lane = threadIdx.x & 63;
  const int wid = threadIdx.x >> 6;
  if (lane == 0) ws[wid] = s;
  __syncthreads();
  if (threadIdx.x == 0) {
    out[0] = (ws[0] + ws[1] + ws[2] + ws[3]) * (1.0f / kBS);  // exact 2^-14
  }
}

}  // namespace

extern "C" void kernel_launch(void* const* d_in, const int* in_sizes, int n_in,
                              void* d_out, int out_size, void* d_ws, size_t ws_size,
                              hipStream_t stream) {
  const float* outputs = (const float*)d_in[0];
  const float* gt_boxes = (const float*)d_in[1];
  const int* gt_labels = (const int*)d_in[2];
  float* out = (float*)d_out;
  float* partials = (float*)d_ws;   // kBlocks floats = 12.25 KB, 16B-aligned

  yolo_loss_kernel<<<kBlocks, kTile, 0, stream>>>(outputs, gt_boxes, gt_labels, partials);
  reduce_kernel<<<1, 256, 0, stream>>>(partials, out);
}

// Round 13
// 25.553 us; speedup vs baseline: 1.0275x; 1.0275x over previous
//
#include <hip/hip_runtime.h>

namespace {

constexpr int kS = 7;
constexpr int kC = 20;
constexpr int kN = 8;
constexpr int kBS = 16384;
constexpr int kCells = kBS * kS * kS;   // 802816 = 3136 * 256
constexpr int kTile = 256;              // cells per tile (= block size)
constexpr int kNT = kCells / kTile;     // 3136 tiles
constexpr int kGrid = 1280;             // 5 blocks/CU exactly, all resident
constexpr int kF = 30;                  // floats per cell (120 B)
constexpr float kLambdaCoord = 5.0f;
constexpr float kLambdaNoobj = 0.5f;
constexpr float kEps = 1e-6f;

typedef const __attribute__((address_space(1))) unsigned int gu32;
typedef __attribute__((address_space(3))) unsigned int lu32;

__global__ __launch_bounds__(256) void yolo_loss_kernel(
    const float* __restrict__ outputs,   // [BS,7,7,30]
    const float* __restrict__ gt_boxes,  // [BS,8,4]
    const int* __restrict__ gt_labels,   // [BS,8]
    float* __restrict__ partials) {      // [kGrid]
  __shared__ float lds[kTile * kF];      // 30 KB transpose buffer
  __shared__ float ws[4];

  const int tid = threadIdx.x;
  const int lane = tid & 63;
  const int w = tid >> 6;                // wave id, uniform per wave

  float val = 0.0f;

  // Persistent loop: block b handles tiles b, b+1280, b+2560. Waves are
  // fully independent across iterations (wave-private LDS slices) -> NO
  // barrier in the loop; only wave-local waitcnt fences.
  for (int t = blockIdx.x; t < kNT; t += kGrid) {
    // Prior iteration's ds_reads must complete before the DMA may overwrite
    // this wave's slice (compiler cannot see the DMA->LDS dependence).
    asm volatile("s_waitcnt lgkmcnt(0)" ::: "memory");

    // ---- WAVE-PRIVATE async DMA stage: wave w stages its own 64 cells
    //      (7680 B) as 7 full 1 KB global_load_lds + 1 half (lanes 0-31).
    {
      const char* srcb = reinterpret_cast<const char*>(outputs) +
                         ((size_t)t * kTile + (size_t)w * 64) * 120;
      char* dstb = reinterpret_cast<char*>(lds) + w * 7680;
#pragma unroll
      for (int k = 0; k < 7; ++k) {
        __builtin_amdgcn_global_load_lds((gu32*)(srcb + k * 1024 + lane * 16),
                                         (lu32*)(dstb + k * 1024 + lane * 16),
                                         16, 0, 0);
      }
      if (lane < 32) {
        __builtin_amdgcn_global_load_lds((gu32*)(srcb + 7168 + lane * 16),
                                         (lu32*)(dstb + 7168 + lane * 16),
                                         16, 0, 0);
      }
    }

    // ---- gt loads issue now; latency overlaps the DMA ----
    const int c = t * kTile + tid;
    const int bs = c / (kS * kS);
    float g[kN][4];
    const float4* gb4 =
        reinterpret_cast<const float4*>(gt_boxes + (size_t)bs * kN * 4);
#pragma unroll
    for (int n = 0; n < kN; ++n) {
      float4 v = gb4[n];
      g[n][0] = v.x; g[n][1] = v.y; g[n][2] = v.z; g[n][3] = v.w;
    }
    const int4* lb4 = reinterpret_cast<const int4*>(gt_labels + (size_t)bs * kN);
    const int4 lab0 = lb4[0];
    const int4 lab1 = lb4[1];

    // ---- precompute gt corners/areas once (overlaps DMA flight) ----
    float gx1[kN], gx2[kN], gy1[kN], gy2[kN], ga[kN];
#pragma unroll
    for (int n = 0; n < kN; ++n) {
      gx1[n] = g[n][0] - g[n][2] * 0.5f;
      gx2[n] = g[n][0] + g[n][2] * 0.5f;
      gy1[n] = g[n][1] - g[n][3] * 0.5f;
      gy2[n] = g[n][1] + g[n][3] * 0.5f;
      ga[n]  = g[n][2] * g[n][3];
    }

    // ---- wave-local drain of the DMA (also covers gt loads) ----
    asm volatile("s_waitcnt vmcnt(0)" ::: "memory");

    // per-thread cell in LDS; word-stride 30 across lanes
    const float* x = lds + tid * kF;

    // ---- pairwise IOU (v_rcp_f32: ~1ulp, far below the 5.56 threshold) ----
    float iou[2][kN];
#pragma unroll
    for (int b = 0; b < 2; ++b) {
      const float px = x[b * 5 + 0], py = x[b * 5 + 1];
      const float pw = x[b * 5 + 2], ph = x[b * 5 + 3];
      const float px1 = px - pw * 0.5f, px2 = px + pw * 0.5f;
      const float py1 = py - ph * 0.5f, py2 = py + ph * 0.5f;
      const float parea = pw * ph;
#pragma unroll
      for (int n = 0; n < kN; ++n) {
        const float iw = fmaxf(fminf(px2, gx2[n]) - fmaxf(px1, gx1[n]), 0.0f);
        const float ih = fmaxf(fminf(py2, gy2[n]) - fmaxf(py1, gy1[n]), 0.0f);
        const float inter = iw * ih;
        const float uni = parea + ga[n] - inter;
        iou[b][n] = inter * __builtin_amdgcn_rcpf(uni + kEps);
      }
    }

    // ---- j_star scan (first-max wins, matches jnp.argmax) ----
    float best_iou = -1.0f;
    float i0j = 0.0f, i1j = 0.0f;
#pragma unroll
    for (int n = 0; n < kN; ++n) {
      const float m = fmaxf(iou[0][n], iou[1][n]);
      if (m > best_iou) { best_iou = m; i0j = iou[0][n]; i1j = iou[1][n]; }
    }
    const int bb = (i1j > i0j) ? 1 : 0;   // index 0 wins ties

    // ---- selections (reference quirk: best_b indexes gt_boxes' N axis) ----
    const float gsx = bb ? g[1][0] : g[0][0];
    const float gsy = bb ? g[1][1] : g[0][1];
    const float gsw = bb ? g[1][2] : g[0][2];
    const float gsh = bb ? g[1][3] : g[0][3];
    const float psx = bb ? x[5] : x[0];
    const float psy = bb ? x[6] : x[1];
    const float psw = bb ? x[7] : x[2];
    const float psh = bb ? x[8] : x[3];
    const float psc = bb ? x[9] : x[4];

    // ---- localization + confidence (raw v_sqrt_f32: ~1ulp) ----
    const float dx = psx - gsx;
    const float dy = psy - gsy;
    const float dw = __builtin_amdgcn_sqrtf(psw) - __builtin_amdgcn_sqrtf(gsw);
    const float dh = __builtin_amdgcn_sqrtf(psh) - __builtin_amdgcn_sqrtf(gsh);
    const float loc = kLambdaCoord * (dx * dx + dy * dy + dw * dw + dh * dh);
    const float conf_obj = (psc - best_iou) * (psc - best_iou);

    // ---- log-sum-exp over 20 classes (inputs in [0,1): no max pass);
    //      4 accumulators shorten the dependence chain ----
    float se0 = 0.0f, se1 = 0.0f, se2 = 0.0f, se3 = 0.0f;
#pragma unroll
    for (int k = 0; k < kC; k += 4) {
      se0 += __expf(x[10 + k + 0]);
      se1 += __expf(x[10 + k + 1]);
      se2 += __expf(x[10 + k + 2]);
      se3 += __expf(x[10 + k + 3]);
    }
    const float lse = __logf((se0 + se1) + (se2 + se3));

    // ---- CE over the 8 labels (dynamic LDS gather) ----
    float s8 = 0.0f;
    s8 += x[10 + lab0.x] + x[10 + lab0.y] + x[10 + lab0.z] + x[10 + lab0.w];
    s8 += x[10 + lab1.x] + x[10 + lab1.y] + x[10 + lab1.z] + x[10 + lab1.w];
    const float ce = lse - 0.125f * s8;   // == -(s8 - 8*lse)/8

    // ---- noobj ----
    const float noobj = kLambdaNoobj * (x[4] * x[4] + x[9] * x[9]);

    val += (best_iou > 0.0f) ? (loc + conf_obj + ce) : noobj;
  }

  // ---- block reduction: wave64 shuffle, then LDS across the 4 waves ----
#pragma unroll
  for (int off = 32; off > 0; off >>= 1) val += __shfl_down(val, off, 64);
  if (lane == 0) ws[w] = val;
  __syncthreads();
  if (tid == 0) {
    partials[blockIdx.x] = ws[0] + ws[1] + ws[2] + ws[3];  // NO atomic
  }
}

__global__ __launch_bounds__(256) void reduce_kernel(
    const float* __restrict__ partials, float* __restrict__ out) {
  // 1280 floats = 320 float4; 256 threads -> 2 rounds
  const float4* p4 = reinterpret_cast<const float4*>(partials);
  float s = 0.0f;
  for (int i = threadIdx.x; i < kGrid / 4; i += 256) {
    const float4 v = p4[i];
    s += (v.x + v.y) + (v.z + v.w);
  }
#pragma unroll
  for (int off = 32; off > 0; off >>= 1) s += __shfl_down(s, off, 64);
  __shared__ float ws[4];
  const int lane = threadIdx.x & 63;
  const int wid = threadIdx.x >> 6;
  if (lane == 0) ws[wid] = s;
  __syncthreads();
  if (threadIdx.x == 0) {
    out[0] = (ws[0] + ws[1] + ws[2] + ws[3]) * (1.0f / kBS);  // exact 2^-14
  }
}

}  // namespace

extern "C" void kernel_launch(void* const* d_in, const int* in_sizes, int n_in,
                              void* d_out, int out_size, void* d_ws, size_t ws_size,
                              hipStream_t stream) {
  const float* outputs = (const float*)d_in[0];
  const float* gt_boxes = (const float*)d_in[1];
  const int* gt_labels = (const int*)d_in[2];
  float* out = (float*)d_out;
  float* partials = (float*)d_ws;   // kGrid floats = 5 KB, 16B-aligned

  yolo_loss_kernel<<<kGrid, kTile, 0, stream>>>(outputs, gt_boxes, gt_labels, partials);
  reduce_kernel<<<1, 256, 0, stream>>>(partials, out);
}